// Round 6
// baseline (1136.300 us; speedup 1.0000x reference)
//
#include <hip/hip_runtime.h>
#include <hip/hip_fp16.h>

// GCN encoder: out = A @ ( relu(A @ (X W1)) W2 ),  A = COO scatter (dst <- src)
// N=100000 nodes, E=1600000 edges, F_IN=128, H1=64, H2=32, all f32.
//
// Round 6: no node-level sort. Edges binned once into fixed-capacity 512-node
// buckets (pass1, fused with gemm1). Each layer's SpMM is a per-bucket kernel
// that LDS-accumulates f32 and, for layer 1, fuses relu+W2 in-block (h1 never
// materialized). hist/scan/pass2/gemm2 kernels all eliminated.

constexpr int N_NODES = 100000;
constexpr int N_EDGES = 1600000;
constexpr int F_IN = 128;
constexpr int H1 = 64;
constexpr int H2 = 32;
constexpr int BSHIFT = 9;                         // 512 nodes per bucket
constexpr int BNODES = 1 << BSHIFT;
constexpr int NBUCK = (N_NODES + BNODES - 1) / BNODES;  // 196
constexpr int CAP = 10240;                        // per-bucket staging capacity
                                                  // (mean 8192, sigma~90 -> 22 sigma slack)
constexpr int CHUNK = 2048;                       // edges per pass1 workgroup
constexpr int P1_WGS = (N_EDGES + CHUNK - 1) / CHUNK;  // 782
constexpr int GEMM_WGS = (N_NODES + 255) / 256;        // 391
constexpr int TILE_N = 16;                        // W1 column tile (8KB LDS)

// ---------------- cursor init: cursor[b] = b*CAP ---------------------------
__global__ __launch_bounds__(256) void init_cursors(int* __restrict__ cursor)
{
    int t = threadIdx.x;
    if (t < NBUCK) cursor[t] = t * CAP;
}

// ---- pass1: bin edges by dst>>9 into fixed-capacity staging (+ gemm1) -----
// staging record: .x = src | (dst_low9 << 17)   (src < 2^17), .y = w bits
__global__ __launch_bounds__(256) void pass1_bin_gemm1(
    const int* __restrict__ src, const int* __restrict__ dst,
    const float* __restrict__ w, int* __restrict__ cursor,
    int2* __restrict__ staging,
    const float* __restrict__ X, const float* __restrict__ W1,
    __half* __restrict__ xw1out)
{
    __shared__ float smem[F_IN * TILE_N];            // 8 KiB (both roles)

    if (blockIdx.x >= P1_WGS) {
        // ---------------- gemm_xw1 role (tiled W1, fp16 out) ----------------
        int row = (blockIdx.x - P1_WGS) * 256 + threadIdx.x;
        bool alive = row < N_NODES;
        const float4* xr = alive
            ? reinterpret_cast<const float4*>(X + (size_t)row * F_IN) : nullptr;
        __half2* oh = alive
            ? reinterpret_cast<__half2*>(xw1out + (size_t)row * H1) : nullptr;

        for (int t = 0; t < H1 / TILE_N; ++t) {
            for (int i = threadIdx.x; i < F_IN * TILE_N; i += 256) {
                int k = i >> 4, j = i & 15;
                smem[i] = W1[(size_t)k * H1 + t * TILE_N + j];
            }
            __syncthreads();
            if (alive) {
                float4 acc[TILE_N / 4];
#pragma unroll
                for (int j = 0; j < TILE_N / 4; ++j)
                    acc[j] = make_float4(0.f, 0.f, 0.f, 0.f);
                for (int k4 = 0; k4 < F_IN / 4; ++k4) {
                    float4 xv = xr[k4];
#pragma unroll
                    for (int kk = 0; kk < 4; ++kk) {
                        float xk = (kk == 0) ? xv.x : (kk == 1) ? xv.y
                                 : (kk == 2) ? xv.z : xv.w;
                        const float4* wr = reinterpret_cast<const float4*>(
                            &smem[(k4 * 4 + kk) * TILE_N]);
#pragma unroll
                        for (int j = 0; j < TILE_N / 4; ++j) {
                            float4 wv = wr[j];
                            acc[j].x += xk * wv.x;
                            acc[j].y += xk * wv.y;
                            acc[j].z += xk * wv.z;
                            acc[j].w += xk * wv.w;
                        }
                    }
                }
#pragma unroll
                for (int j = 0; j < TILE_N / 4; ++j) {
                    oh[t * (TILE_N / 2) + j * 2 + 0] =
                        __floats2half2_rn(acc[j].x, acc[j].y);
                    oh[t * (TILE_N / 2) + j * 2 + 1] =
                        __floats2half2_rn(acc[j].z, acc[j].w);
                }
            }
            __syncthreads();
        }
        return;
    }

    // ---------------- binning role ----------------
    int* lcnt  = (int*)smem;        // [256] counters, then reused as cursors
    int* lbase = lcnt + 256;        // [256] reserved global bases

    int e0 = blockIdx.x * CHUNK;
    int nhere = N_EDGES - e0; if (nhere > CHUNK) nhere = CHUNK;

    lcnt[threadIdx.x] = 0;
    __syncthreads();

    int   es[CHUNK / 256];
    int   ed[CHUNK / 256];
    float ew[CHUNK / 256];
#pragma unroll
    for (int k = 0; k < CHUNK / 256; ++k) {
        int local = k * 256 + threadIdx.x;
        bool v = local < nhere;
        int idx = e0 + local;
        es[k] = v ? src[idx] : 0;
        ed[k] = v ? dst[idx] : -1;
        ew[k] = v ? w[idx] : 0.f;
        if (v) atomicAdd(&lcnt[ed[k] >> BSHIFT], 1);
    }
    __syncthreads();
    if (threadIdx.x < NBUCK) {
        int c = lcnt[threadIdx.x];
        lbase[threadIdx.x] = (c > 0) ? atomicAdd(&cursor[threadIdx.x], c) : 0;
    }
    __syncthreads();
    lcnt[threadIdx.x] = 0;                            // reuse as cursors
    __syncthreads();
#pragma unroll
    for (int k = 0; k < CHUNK / 256; ++k) {
        if (ed[k] >= 0) {
            int b = ed[k] >> BSHIFT;
            int r = atomicAdd(&lcnt[b], 1);
            int pos = lbase[b] + r;
            if (pos < (b + 1) * CAP)                  // capacity guard
                staging[pos] = make_int2(
                    es[k] | ((ed[k] & (BNODES - 1)) << 17),
                    __float_as_int(ew[k]));
        }
    }
}

// ---- layer 1: per-bucket LDS-accumulate SpMM + fused relu + W2 GEMM -------
// acc: 512 nodes x 64 feats f32 = 128KB LDS; w2s: 8KB. One block per bucket.
__global__ __launch_bounds__(1024) void spmm_bucket1(
    const int* __restrict__ cursor, const int2* __restrict__ staging,
    const __half* __restrict__ xw1h, const float* __restrict__ W2,
    __half* __restrict__ h1w2h)
{
    __shared__ float acc[BNODES * H1];                // 128 KiB
    __shared__ float w2s[H1 * H2];                    // 8 KiB

    int b = blockIdx.x;
    int t = threadIdx.x;
    for (int i = t; i < H1 * H2; i += 1024) w2s[i] = W2[i];
    for (int i = t; i < BNODES * H1; i += 1024) acc[i] = 0.f;
    __syncthreads();

    int base = b * CAP;
    int cnt = cursor[b] - base;
    int wid = t >> 6, lane = t & 63;                  // 16 waves, lane = feature

    int i = wid;
    for (; i + 48 < cnt; i += 64) {                   // 4 edges per wave per iter
        int2 c0 = staging[base + i];
        int2 c1 = staging[base + i + 16];
        int2 c2 = staging[base + i + 32];
        int2 c3 = staging[base + i + 48];
        float v0 = __int_as_float(c0.y) *
                   __half2float(xw1h[(size_t)(c0.x & 0x1FFFF) * H1 + lane]);
        float v1 = __int_as_float(c1.y) *
                   __half2float(xw1h[(size_t)(c1.x & 0x1FFFF) * H1 + lane]);
        float v2 = __int_as_float(c2.y) *
                   __half2float(xw1h[(size_t)(c2.x & 0x1FFFF) * H1 + lane]);
        float v3 = __int_as_float(c3.y) *
                   __half2float(xw1h[(size_t)(c3.x & 0x1FFFF) * H1 + lane]);
        atomicAdd(&acc[((c0.x >> 17) & (BNODES - 1)) * H1 + lane], v0);
        atomicAdd(&acc[((c1.x >> 17) & (BNODES - 1)) * H1 + lane], v1);
        atomicAdd(&acc[((c2.x >> 17) & (BNODES - 1)) * H1 + lane], v2);
        atomicAdd(&acc[((c3.x >> 17) & (BNODES - 1)) * H1 + lane], v3);
    }
    for (; i < cnt; i += 16) {
        int2 c = staging[base + i];
        atomicAdd(&acc[((c.x >> 17) & (BNODES - 1)) * H1 + lane],
                  __int_as_float(c.y) *
                  __half2float(xw1h[(size_t)(c.x & 0x1FFFF) * H1 + lane]));
    }
    __syncthreads();

    // relu(acc) @ W2 -> h1w2h (fp16). thread -> (row r, col half cb)
    int r = t >> 1;
    int cb = (t & 1) * 16;
    int node = (b << BSHIFT) + r;
    if (node < N_NODES) {
        float o[16];
#pragma unroll
        for (int j = 0; j < 16; ++j) o[j] = 0.f;
        for (int k = 0; k < H1; ++k) {
            float a = fmaxf(acc[r * H1 + k], 0.f);
            const float* wr = &w2s[k * H2 + cb];
#pragma unroll
            for (int j = 0; j < 16; ++j) o[j] += a * wr[j];
        }
        __half2* oh = reinterpret_cast<__half2*>(h1w2h + (size_t)node * H2 + cb);
#pragma unroll
        for (int j = 0; j < 8; ++j)
            oh[j] = __floats2half2_rn(o[2 * j], o[2 * j + 1]);
    }
}

// ---- layer 2: per-bucket LDS-accumulate SpMM -> out (f32) -----------------
// acc: 512 x 32 f32 = 64KB LDS. Half-wave (32 lanes) per edge.
__global__ __launch_bounds__(1024) void spmm_bucket2(
    const int* __restrict__ cursor, const int2* __restrict__ staging,
    const __half* __restrict__ h1w2h, float* __restrict__ out)
{
    __shared__ float acc[BNODES * H2];                // 64 KiB

    int b = blockIdx.x;
    int t = threadIdx.x;
    for (int i = t; i < BNODES * H2; i += 1024) acc[i] = 0.f;
    __syncthreads();

    int base = b * CAP;
    int cnt = cursor[b] - base;
    int hw = t >> 5, f = t & 31;                      // 32 half-waves, f = feature

    int i = hw;
    for (; i + 96 < cnt; i += 128) {                  // 4 edges per half-wave
        int2 c0 = staging[base + i];
        int2 c1 = staging[base + i + 32];
        int2 c2 = staging[base + i + 64];
        int2 c3 = staging[base + i + 96];
        float v0 = __int_as_float(c0.y) *
                   __half2float(h1w2h[(size_t)(c0.x & 0x1FFFF) * H2 + f]);
        float v1 = __int_as_float(c1.y) *
                   __half2float(h1w2h[(size_t)(c1.x & 0x1FFFF) * H2 + f]);
        float v2 = __int_as_float(c2.y) *
                   __half2float(h1w2h[(size_t)(c2.x & 0x1FFFF) * H2 + f]);
        float v3 = __int_as_float(c3.y) *
                   __half2float(h1w2h[(size_t)(c3.x & 0x1FFFF) * H2 + f]);
        atomicAdd(&acc[((c0.x >> 17) & (BNODES - 1)) * H2 + f], v0);
        atomicAdd(&acc[((c1.x >> 17) & (BNODES - 1)) * H2 + f], v1);
        atomicAdd(&acc[((c2.x >> 17) & (BNODES - 1)) * H2 + f], v2);
        atomicAdd(&acc[((c3.x >> 17) & (BNODES - 1)) * H2 + f], v3);
    }
    for (; i < cnt; i += 32) {
        int2 c = staging[base + i];
        atomicAdd(&acc[((c.x >> 17) & (BNODES - 1)) * H2 + f],
                  __int_as_float(c.y) *
                  __half2float(h1w2h[(size_t)(c.x & 0x1FFFF) * H2 + f]));
    }
    __syncthreads();

    // write out rows of this bucket (coalesced)
    int nvalid = N_NODES - (b << BSHIFT);
    if (nvalid > BNODES) nvalid = BNODES;
    size_t gbase = (size_t)(b << BSHIFT) * H2;
    for (int i = t; i < nvalid * H2; i += 1024) out[gbase + i] = acc[i];
}

extern "C" void kernel_launch(void* const* d_in, const int* in_sizes, int n_in,
                              void* d_out, int out_size, void* d_ws, size_t ws_size,
                              hipStream_t stream)
{
    const float* features    = (const float*)d_in[0];   // [N, 128]
    const float* edge_weight = (const float*)d_in[1];   // [E]
    const float* W1          = (const float*)d_in[2];   // [128, 64]
    const float* W2          = (const float*)d_in[3];   // [64, 32]
    const int*   src         = (const int*)d_in[4];     // [E]
    const int*   dst         = (const int*)d_in[5];     // [E]
    float* out = (float*)d_out;                          // [N, 32]

    // workspace layout (~35.3 MB)
    char* p = (char*)d_ws;
    __half* xw1h   = (__half*)p;    p += (size_t)N_NODES * H1 * 2;        // 12.8MB
    __half* h1w2h  = (__half*)p;    p += (size_t)N_NODES * H2 * 2;        // 6.4MB
    int2*  staging = (int2*)p;      p += (size_t)NBUCK * CAP * 8;         // 16.05MB
    int*   cursor  = (int*)p;       p += 256 * 4;

    init_cursors<<<1, 256, 0, stream>>>(cursor);
    pass1_bin_gemm1<<<P1_WGS + GEMM_WGS, 256, 0, stream>>>(
        src, dst, edge_weight, cursor, staging, features, W1, xw1h);
    spmm_bucket1<<<NBUCK, 1024, 0, stream>>>(cursor, staging, xw1h, W2, h1w2h);
    spmm_bucket2<<<NBUCK, 1024, 0, stream>>>(cursor, staging, h1w2h, out);
}